// Round 8
// baseline (178.519 us; speedup 1.0000x reference)
//
#include <hip/hip_runtime.h>
#include <hip/hip_bf16.h>
#include <stdint.h>
#include <math.h>

// Problem constants (fixed by setup_inputs)
#define BATCH 8192   // B rows of embeddings
#define DIM   2048   // D feature dim
#define KDIR  512    // K directions
#define NPTS  17     // quadrature points

typedef _Float16 half8  __attribute__((ext_vector_type(8)));
typedef float   floatx4 __attribute__((ext_vector_type(4)));

#define AS1 __attribute__((address_space(1)))
#define AS3 __attribute__((address_space(3)))

// async global->LDS, 16B per lane. LDS dest must be wave-uniform base + lane*16.
__device__ __forceinline__ void g2l16(const void* g, void* l) {
    __builtin_amdgcn_global_load_lds((AS1 void*)(uintptr_t)g, (AS3 void*)l, 16u, 0, 0u);
}

// ---------------------------------------------------------------------------
// K1: PREP (unchanged from r7, measured-good). blocks [0,8192): emb fp32->fp16
// (+zero pp/out). blocks [8192,8256): normalize+transpose dir -> dT.
__global__ __launch_bounds__(256) void prep(const float* __restrict__ emb,
                                            const float* __restrict__ dir,
                                            _Float16* __restrict__ A16,
                                            _Float16* __restrict__ dT,
                                            float* __restrict__ pp,
                                            float* __restrict__ out) {
    const int b = blockIdx.x;
    const int t = threadIdx.x;
    if (b < 8192) {
        if (b < 4) pp[b * 256 + t] = 0.f;
        if (b == 4 && t == 0) out[0] = 0.f;
        const size_t i = ((size_t)b * 256 + t) * 8;
        floatx4 a = *(const floatx4*)(emb + i);
        floatx4 c = *(const floatx4*)(emb + i + 4);
        half8 h;
        h[0] = (_Float16)a[0]; h[1] = (_Float16)a[1];
        h[2] = (_Float16)a[2]; h[3] = (_Float16)a[3];
        h[4] = (_Float16)c[0]; h[5] = (_Float16)c[1];
        h[6] = (_Float16)c[2]; h[7] = (_Float16)c[3];
        *(half8*)(A16 + i) = h;
        return;
    }
    const int k0 = (b - 8192) * 8;
    __shared__ _Float16 sv[8][2052];
    __shared__ float    sred[8][32];
    __shared__ float    sinv[8];
    const int g  = t >> 3;
    const int cl = t & 7;
    float ss = 0.f;
    #pragma unroll 8
    for (int it = 0; it < 64; ++it) {
        const int r = it * 32 + g;
        float v = dir[(size_t)r * KDIR + k0 + cl];
        sv[cl][r] = (_Float16)v;
        ss = fmaf(v, v, ss);
    }
    sred[cl][g] = ss;
    __syncthreads();
    if (t < 8) {
        float s = 0.f;
        #pragma unroll
        for (int gg = 0; gg < 32; ++gg) s += sred[t][gg];
        sinv[t] = 1.0f / fmaxf(sqrtf(s), 1e-12f);
    }
    __syncthreads();
    const int c2 = t >> 5;
    const int p  = t & 31;
    const float inv = sinv[c2];
    #pragma unroll
    for (int it2 = 0; it2 < 8; ++it2) {
        const int i0 = p * 8 + it2 * 256;
        half8 h;
        #pragma unroll
        for (int e = 0; e < 8; ++e) h[e] = (_Float16)((float)sv[c2][i0 + e] * inv);
        *(half8*)(dT + (size_t)(k0 + c2) * DIM + i0) = h;
    }
}

// ---------------------------------------------------------------------------
// K2: GEMM (unchanged from r7 — dropped out of top-5, i.e. < 41us).
// 128x64 tiles, 512 blocks = 2 co-resident blocks/CU, g2l16-only staging,
// counted vmcnt, 2-barrier. XCD-bijective remap.
__global__ __launch_bounds__(256, 2) void gemm16(const _Float16* __restrict__ A,
                                                 const _Float16* __restrict__ Bt,
                                                 _Float16* __restrict__ C,
                                                 float* __restrict__ pp) {
    __shared__ _Float16 sA[2][2][128 * 32];   // [stage][panel] 8KB each
    __shared__ _Float16 sB[2][2][64 * 32];    // [stage][panel] 4KB each

    const int tid  = threadIdx.x;
    const int lane = tid & 63;
    const int wave = tid >> 6;
    const int wm = wave & 1;
    const int wn = wave >> 1;

    const int d    = blockIdx.x + 64 * blockIdx.y;   // 0..511
    const int xcd  = d & 7;
    const int slot = d >> 3;
    const int bx   = xcd * 8 + (slot >> 3);
    const int by   = slot & 7;
    const int tm = bx * 128;
    const int tn = by * 64;

    const int srow = tid >> 2;
    const int scol = (tid & 3) * 8;
    const _Float16* baseA = A  + (size_t)(tm + srow) * DIM + scol;
    const _Float16* baseB = Bt + (size_t)(tn + srow) * DIM + scol;

#define ISSUE(IT, ST)                                                         \
    do {                                                                      \
        const _Float16* pa = baseA + (IT) * 64;                               \
        const _Float16* pb = baseB + (IT) * 64;                               \
        g2l16(pa,                 (char*)&sA[ST][0][0] + tid * 16);           \
        g2l16(pa + 64 * DIM,      (char*)&sA[ST][0][0] + 4096 + tid * 16);    \
        g2l16(pa + 32,            (char*)&sA[ST][1][0] + tid * 16);           \
        g2l16(pa + 64 * DIM + 32, (char*)&sA[ST][1][0] + 4096 + tid * 16);    \
        g2l16(pb,                 (char*)&sB[ST][0][0] + tid * 16);           \
        g2l16(pb + 32,            (char*)&sB[ST][1][0] + tid * 16);           \
    } while (0)

    const floatx4 zero = {0.f, 0.f, 0.f, 0.f};
    floatx4 acc[4][2];
    #pragma unroll
    for (int i = 0; i < 4; ++i)
        #pragma unroll
        for (int j = 0; j < 2; ++j) acc[i][j] = zero;

    const int mrow = lane & 15;
    const int kk   = (lane >> 4) * 8;

    ISSUE(0, 0);

    const int NIT = DIM / 64;                      // 32
    for (int it = 0; it < NIT; ++it) {
        const int s = it & 1;
        if (it + 1 < NIT) {
            ISSUE(it + 1, (it + 1) & 1);
            asm volatile("s_waitcnt vmcnt(6)" ::: "memory");
        } else {
            asm volatile("s_waitcnt vmcnt(0)" ::: "memory");
        }
        asm volatile("s_barrier" ::: "memory");

        half8 a0[4], a1[4], b0[2], b1[2];
        #pragma unroll
        for (int f = 0; f < 4; ++f) {
            a0[f] = *(const half8*)(&sA[s][0][(size_t)(wm * 64 + f * 16 + mrow) * 32 + kk]);
            a1[f] = *(const half8*)(&sA[s][1][(size_t)(wm * 64 + f * 16 + mrow) * 32 + kk]);
        }
        #pragma unroll
        for (int f = 0; f < 2; ++f) {
            b0[f] = *(const half8*)(&sB[s][0][(size_t)(wn * 32 + f * 16 + mrow) * 32 + kk]);
            b1[f] = *(const half8*)(&sB[s][1][(size_t)(wn * 32 + f * 16 + mrow) * 32 + kk]);
        }
        #pragma unroll
        for (int i = 0; i < 4; ++i)
            #pragma unroll
            for (int j = 0; j < 2; ++j) {
                acc[i][j] = __builtin_amdgcn_mfma_f32_16x16x32_f16(a0[i], b0[j], acc[i][j], 0, 0, 0);
                acc[i][j] = __builtin_amdgcn_mfma_f32_16x16x32_f16(a1[i], b1[j], acc[i][j], 0, 0, 0);
            }
        asm volatile("s_waitcnt lgkmcnt(0)" ::: "memory");
        asm volatile("s_barrier" ::: "memory");
    }
#undef ISSUE

    const int r0 = (lane >> 4) * 4;
    const int cn = lane & 15;
    #pragma unroll
    for (int i = 0; i < 4; ++i) {
        #pragma unroll
        for (int j = 0; j < 2; ++j) {
            const int row = tm + wm * 64 + i * 16 + r0;
            const int col = tn + wn * 32 + j * 16 + cn;
            #pragma unroll
            for (int r = 0; r < 4; ++r)
                C[(size_t)(row + r) * KDIR + col] = (_Float16)acc[i][j][r];
        }
    }

    #pragma unroll
    for (int j = 0; j < 2; ++j) {
        float s = 0.f, q = 0.f;
        #pragma unroll
        for (int i = 0; i < 4; ++i)
            #pragma unroll
            for (int r = 0; r < 4; ++r) {
                float v = acc[i][j][r];
                s += v;
                q = fmaf(v, v, q);
            }
        s += __shfl_down(s, 32, 64); q += __shfl_down(q, 32, 64);
        s += __shfl_down(s, 16, 64); q += __shfl_down(q, 16, 64);
        if (lane < 16) {
            const int col = tn + wn * 32 + j * 16 + lane;
            atomicAdd(&pp[col], s);
            atomicAdd(&pp[KDIR + col], q);
        }
    }
}

// ---------------------------------------------------------------------------
// K3: ECF partials — REWRITTEN (est. 40-50us by cross-round budget algebra).
// Defects fixed: (a) 4.2M scalar 2-byte global loads (stride 1KB) -> LDS
// staging via half8 (16B/lane, coalesced, 4 loads/thread); (b) spill risk
// from unroll-8 x 34 live accumulators -> unroll 2 (~60 VGPR, no spill).
// LDS rows padded to 264 halfs: ds_read_u16 at fixed col across rows is
// 2 lanes/bank = free. Math identical (one fold: (2/17)*(1/2pi) premul).
__global__ __launch_bounds__(256) void ecf_p1(const _Float16* __restrict__ proj,
                                              const float* __restrict__ pp,
                                              float* __restrict__ pecf) {
    const int ch   = blockIdx.x >> 1;                    // 0..255
    const int half = blockIdx.x & 1;
    const int t    = threadIdx.x;
    const int c    = half * 256 + t;                     // 0..511
    const double s_  = (double)pp[c];
    const double s2_ = (double)pp[KDIR + c];
    const double mm  = s_ / (double)BATCH;
    const double var = (s2_ - (double)BATCH * mm * mm) / (double)(BATCH - 1);
    const float m   = (float)mm;
    const float sdi = (float)(1.0 / (sqrt(var) + 1e-8));

    // stage this block's 32-row x 256-col tile (16KB) with vector loads
    __shared__ _Float16 sv[32][264];                     // pad: 528B rows
    const _Float16* src = proj + (size_t)(ch * 32) * KDIR + half * 256;
    #pragma unroll
    for (int l = 0; l < 4; ++l) {
        const int idx = l * 256 + t;                     // 0..1023
        const int row = idx >> 5;                        // 0..31
        const int chk = idx & 31;                        // 16B chunk in 512B
        *(half8*)&sv[row][chk * 8] =
            *(const half8*)(src + (size_t)row * KDIR + chk * 8);
    }
    __syncthreads();

    float cr[NPTS], ci[NPTS];
    #pragma unroll
    for (int i = 0; i < NPTS; ++i) { cr[i] = 0.f; ci[i] = 0.f; }

    // rev = z * (2/17) / (2*pi); |rev| <= ~0.12 — native sin/cos safe
    const float K1 = (2.0f / 17.0f) * 0.15915494309189535f;
    #pragma unroll 2
    for (int r = 0; r < 32; ++r) {
        float z = ((float)sv[r][t] - m) * sdi;
        const float rev = z * K1;
        float s1 = __builtin_amdgcn_sinf(rev);           // v_sin_f32
        float c1 = __builtin_amdgcn_cosf(rev);           // v_cos_f32
        const float tc = 2.0f * c1;
        float cm = 1.0f, sm = 0.0f;
        float ck = c1,  sk = s1;
        cr[0] += ck; ci[0] += sk;
        #pragma unroll
        for (int k = 1; k < NPTS; ++k) {
            float cn_ = fmaf(tc, ck, -cm);
            float sn_ = fmaf(tc, sk, -sm);
            cm = ck; sm = sk;
            ck = cn_; sk = sn_;
            cr[k] += ck; ci[k] += sk;
        }
    }
    #pragma unroll
    for (int i = 0; i < NPTS; ++i) {
        pecf[(size_t)((ch * NPTS + i) * 2 + 0) * KDIR + c] = cr[i];
        pecf[(size_t)((ch * NPTS + i) * 2 + 1) * KDIR + c] = ci[i];
    }
}

// K4 (merged p2a+p2b, unchanged from r7): 34 blocks; sum 256 chunks from
// pecf, integrand, block-reduce, atomic.
__global__ __launch_bounds__(256) void ecf_fin(const float* __restrict__ pecf,
                                               float* __restrict__ out) {
    const int i = blockIdx.x >> 1;                       // 0..16
    const int c = (blockIdx.x & 1) * 256 + threadIdx.x;  // 0..511
    double sc = 0.0, ss = 0.0;
    #pragma unroll 4
    for (int ch = 0; ch < 256; ++ch) {
        sc += (double)pecf[(size_t)((ch * NPTS + i) * 2 + 0) * KDIR + c];
        ss += (double)pecf[(size_t)((ch * NPTS + i) * 2 + 1) * KDIR + c];
    }
    const double R = sc / (double)BATCH;
    const double I = ss / (double)BATCH;
    const double t = (2.0 / 17.0) * (double)(i + 1);
    const double tau = exp(-0.5 * t * t);
    const double w = (i == 0 || i == NPTS - 1) ? (1.0 / 17.0) : (2.0 / 17.0);
    const double dR = R - tau;
    double contrib = w * (dR * dR + I * I) / (double)KDIR;

    __shared__ double red[256];
    red[threadIdx.x] = contrib;
    __syncthreads();
    for (int s = 128; s > 0; s >>= 1) {
        if (threadIdx.x < s) red[threadIdx.x] += red[threadIdx.x + s];
        __syncthreads();
    }
    if (threadIdx.x == 0) atomicAdd(out, (float)red[0]);
}

// ---------------------------------------------------------------------------
extern "C" void kernel_launch(void* const* d_in, const int* in_sizes, int n_in,
                              void* d_out, int out_size, void* d_ws, size_t ws_size,
                              hipStream_t stream) {
    const float* emb = (const float*)d_in[0];   // (8192, 2048) fp32
    const float* dir = (const float*)d_in[1];   // (2048, 512) fp32
    float* out = (float*)d_out;

    char* ws = (char*)d_ws;
    // pecf aliases the A16 region (dead after GEMM).
    _Float16* A16  = (_Float16*)(ws + 0);               // 33,554,432 B
    float*    pecf = (float*)   (ws + 0);               // 17,825,792 B (after GEMM)
    _Float16* dT   = (_Float16*)(ws + 33554432);        //  2,097,152 B
    _Float16* proj = (_Float16*)(ws + 35651584);        //  8,388,608 B
    float*    pp   = (float*)   (ws + 44040192);        //      4,096 B

    prep<<<8256, 256, 0, stream>>>(emb, dir, A16, dT, pp, out);
    gemm16<<<dim3(BATCH / 128, KDIR / 64), 256, 0, stream>>>(A16, dT, proj, pp);
    ecf_p1<<<512, 256, 0, stream>>>(proj, pp, pecf);
    ecf_fin<<<34, 256, 0, stream>>>(pecf, out);
}

// Round 9
// 157.742 us; speedup vs baseline: 1.1317x; 1.1317x over previous
//
#include <hip/hip_runtime.h>
#include <hip/hip_bf16.h>
#include <stdint.h>
#include <math.h>

// Problem constants (fixed by setup_inputs)
#define BATCH 8192   // B rows of embeddings
#define DIM   2048   // D feature dim
#define KDIR  512    // K directions
#define NPTS  17     // quadrature points

typedef _Float16 half8  __attribute__((ext_vector_type(8)));
typedef float   floatx4 __attribute__((ext_vector_type(4)));

#define AS1 __attribute__((address_space(1)))
#define AS3 __attribute__((address_space(3)))

// async global->LDS, 16B per lane. LDS dest must be wave-uniform base + lane*16.
__device__ __forceinline__ void g2l16(const void* g, void* l) {
    __builtin_amdgcn_global_load_lds((AS1 void*)(uintptr_t)g, (AS3 void*)l, 16u, 0, 0u);
}

// ---------------------------------------------------------------------------
// K1: PREP (unchanged, measured-good). blocks [0,8192): emb fp32->fp16
// (+zero pp/out). blocks [8192,8256): normalize+transpose dir -> dT.
__global__ __launch_bounds__(256) void prep(const float* __restrict__ emb,
                                            const float* __restrict__ dir,
                                            _Float16* __restrict__ A16,
                                            _Float16* __restrict__ dT,
                                            float* __restrict__ pp,
                                            float* __restrict__ out) {
    const int b = blockIdx.x;
    const int t = threadIdx.x;
    if (b < 8192) {
        if (b < 4) pp[b * 256 + t] = 0.f;
        if (b == 4 && t == 0) out[0] = 0.f;
        const size_t i = ((size_t)b * 256 + t) * 8;
        floatx4 a = *(const floatx4*)(emb + i);
        floatx4 c = *(const floatx4*)(emb + i + 4);
        half8 h;
        h[0] = (_Float16)a[0]; h[1] = (_Float16)a[1];
        h[2] = (_Float16)a[2]; h[3] = (_Float16)a[3];
        h[4] = (_Float16)c[0]; h[5] = (_Float16)c[1];
        h[6] = (_Float16)c[2]; h[7] = (_Float16)c[3];
        *(half8*)(A16 + i) = h;
        return;
    }
    const int k0 = (b - 8192) * 8;
    __shared__ _Float16 sv[8][2052];
    __shared__ float    sred[8][32];
    __shared__ float    sinv[8];
    const int g  = t >> 3;
    const int cl = t & 7;
    float ss = 0.f;
    #pragma unroll 8
    for (int it = 0; it < 64; ++it) {
        const int r = it * 32 + g;
        float v = dir[(size_t)r * KDIR + k0 + cl];
        sv[cl][r] = (_Float16)v;
        ss = fmaf(v, v, ss);
    }
    sred[cl][g] = ss;
    __syncthreads();
    if (t < 8) {
        float s = 0.f;
        #pragma unroll
        for (int gg = 0; gg < 32; ++gg) s += sred[t][gg];
        sinv[t] = 1.0f / fmaxf(sqrtf(s), 1e-12f);
    }
    __syncthreads();
    const int c2 = t >> 5;
    const int p  = t & 31;
    const float inv = sinv[c2];
    #pragma unroll
    for (int it2 = 0; it2 < 8; ++it2) {
        const int i0 = p * 8 + it2 * 256;
        half8 h;
        #pragma unroll
        for (int e = 0; e < 8; ++e) h[e] = (_Float16)((float)sv[c2][i0 + e] * inv);
        *(half8*)(dT + (size_t)(k0 + c2) * DIM + i0) = h;
    }
}

// ---------------------------------------------------------------------------
// K2: GEMM (unchanged — profiled <41us). 128x64 tiles, 512 blocks = 2
// co-resident blocks/CU, g2l16-only staging, counted vmcnt, 2-barrier,
// XCD-bijective remap.
__global__ __launch_bounds__(256, 2) void gemm16(const _Float16* __restrict__ A,
                                                 const _Float16* __restrict__ Bt,
                                                 _Float16* __restrict__ C,
                                                 float* __restrict__ pp) {
    __shared__ _Float16 sA[2][2][128 * 32];   // [stage][panel] 8KB each
    __shared__ _Float16 sB[2][2][64 * 32];    // [stage][panel] 4KB each

    const int tid  = threadIdx.x;
    const int lane = tid & 63;
    const int wave = tid >> 6;
    const int wm = wave & 1;
    const int wn = wave >> 1;

    const int d    = blockIdx.x + 64 * blockIdx.y;   // 0..511
    const int xcd  = d & 7;
    const int slot = d >> 3;
    const int bx   = xcd * 8 + (slot >> 3);
    const int by   = slot & 7;
    const int tm = bx * 128;
    const int tn = by * 64;

    const int srow = tid >> 2;
    const int scol = (tid & 3) * 8;
    const _Float16* baseA = A  + (size_t)(tm + srow) * DIM + scol;
    const _Float16* baseB = Bt + (size_t)(tn + srow) * DIM + scol;

#define ISSUE(IT, ST)                                                         \
    do {                                                                      \
        const _Float16* pa = baseA + (IT) * 64;                               \
        const _Float16* pb = baseB + (IT) * 64;                               \
        g2l16(pa,                 (char*)&sA[ST][0][0] + tid * 16);           \
        g2l16(pa + 64 * DIM,      (char*)&sA[ST][0][0] + 4096 + tid * 16);    \
        g2l16(pa + 32,            (char*)&sA[ST][1][0] + tid * 16);           \
        g2l16(pa + 64 * DIM + 32, (char*)&sA[ST][1][0] + 4096 + tid * 16);    \
        g2l16(pb,                 (char*)&sB[ST][0][0] + tid * 16);           \
        g2l16(pb + 32,            (char*)&sB[ST][1][0] + tid * 16);           \
    } while (0)

    const floatx4 zero = {0.f, 0.f, 0.f, 0.f};
    floatx4 acc[4][2];
    #pragma unroll
    for (int i = 0; i < 4; ++i)
        #pragma unroll
        for (int j = 0; j < 2; ++j) acc[i][j] = zero;

    const int mrow = lane & 15;
    const int kk   = (lane >> 4) * 8;

    ISSUE(0, 0);

    const int NIT = DIM / 64;                      // 32
    for (int it = 0; it < NIT; ++it) {
        const int s = it & 1;
        if (it + 1 < NIT) {
            ISSUE(it + 1, (it + 1) & 1);
            asm volatile("s_waitcnt vmcnt(6)" ::: "memory");
        } else {
            asm volatile("s_waitcnt vmcnt(0)" ::: "memory");
        }
        asm volatile("s_barrier" ::: "memory");

        half8 a0[4], a1[4], b0[2], b1[2];
        #pragma unroll
        for (int f = 0; f < 4; ++f) {
            a0[f] = *(const half8*)(&sA[s][0][(size_t)(wm * 64 + f * 16 + mrow) * 32 + kk]);
            a1[f] = *(const half8*)(&sA[s][1][(size_t)(wm * 64 + f * 16 + mrow) * 32 + kk]);
        }
        #pragma unroll
        for (int f = 0; f < 2; ++f) {
            b0[f] = *(const half8*)(&sB[s][0][(size_t)(wn * 32 + f * 16 + mrow) * 32 + kk]);
            b1[f] = *(const half8*)(&sB[s][1][(size_t)(wn * 32 + f * 16 + mrow) * 32 + kk]);
        }
        #pragma unroll
        for (int i = 0; i < 4; ++i)
            #pragma unroll
            for (int j = 0; j < 2; ++j) {
                acc[i][j] = __builtin_amdgcn_mfma_f32_16x16x32_f16(a0[i], b0[j], acc[i][j], 0, 0, 0);
                acc[i][j] = __builtin_amdgcn_mfma_f32_16x16x32_f16(a1[i], b1[j], acc[i][j], 0, 0, 0);
            }
        asm volatile("s_waitcnt lgkmcnt(0)" ::: "memory");
        asm volatile("s_barrier" ::: "memory");
    }
#undef ISSUE

    const int r0 = (lane >> 4) * 4;
    const int cn = lane & 15;
    #pragma unroll
    for (int i = 0; i < 4; ++i) {
        #pragma unroll
        for (int j = 0; j < 2; ++j) {
            const int row = tm + wm * 64 + i * 16 + r0;
            const int col = tn + wn * 32 + j * 16 + cn;
            #pragma unroll
            for (int r = 0; r < 4; ++r)
                C[(size_t)(row + r) * KDIR + col] = (_Float16)acc[i][j][r];
        }
    }

    #pragma unroll
    for (int j = 0; j < 2; ++j) {
        float s = 0.f, q = 0.f;
        #pragma unroll
        for (int i = 0; i < 4; ++i)
            #pragma unroll
            for (int r = 0; r < 4; ++r) {
                float v = acc[i][j][r];
                s += v;
                q = fmaf(v, v, q);
            }
        s += __shfl_down(s, 32, 64); q += __shfl_down(q, 32, 64);
        s += __shfl_down(s, 16, 64); q += __shfl_down(q, 16, 64);
        if (lane < 16) {
            const int col = tn + wn * 32 + j * 16 + lane;
            atomicAdd(&pp[col], s);
            atomicAdd(&pp[KDIR + col], q);
        }
    }
}

// ---------------------------------------------------------------------------
// K3: ECF partials (unchanged from r8): LDS-staged vector loads, native
// sin/cos, unroll 2.
__global__ __launch_bounds__(256) void ecf_p1(const _Float16* __restrict__ proj,
                                              const float* __restrict__ pp,
                                              float* __restrict__ pecf) {
    const int ch   = blockIdx.x >> 1;                    // 0..255
    const int half = blockIdx.x & 1;
    const int t    = threadIdx.x;
    const int c    = half * 256 + t;                     // 0..511
    const double s_  = (double)pp[c];
    const double s2_ = (double)pp[KDIR + c];
    const double mm  = s_ / (double)BATCH;
    const double var = (s2_ - (double)BATCH * mm * mm) / (double)(BATCH - 1);
    const float m   = (float)mm;
    const float sdi = (float)(1.0 / (sqrt(var) + 1e-8));

    __shared__ _Float16 sv[32][264];                     // pad: 528B rows
    const _Float16* src = proj + (size_t)(ch * 32) * KDIR + half * 256;
    #pragma unroll
    for (int l = 0; l < 4; ++l) {
        const int idx = l * 256 + t;                     // 0..1023
        const int row = idx >> 5;                        // 0..31
        const int chk = idx & 31;                        // 16B chunk in 512B
        *(half8*)&sv[row][chk * 8] =
            *(const half8*)(src + (size_t)row * KDIR + chk * 8);
    }
    __syncthreads();

    float cr[NPTS], ci[NPTS];
    #pragma unroll
    for (int i = 0; i < NPTS; ++i) { cr[i] = 0.f; ci[i] = 0.f; }

    const float K1 = (2.0f / 17.0f) * 0.15915494309189535f;
    #pragma unroll 2
    for (int r = 0; r < 32; ++r) {
        float z = ((float)sv[r][t] - m) * sdi;
        const float rev = z * K1;
        float s1 = __builtin_amdgcn_sinf(rev);           // v_sin_f32
        float c1 = __builtin_amdgcn_cosf(rev);           // v_cos_f32
        const float tc = 2.0f * c1;
        float cm = 1.0f, sm = 0.0f;
        float ck = c1,  sk = s1;
        cr[0] += ck; ci[0] += sk;
        #pragma unroll
        for (int k = 1; k < NPTS; ++k) {
            float cn_ = fmaf(tc, ck, -cm);
            float sn_ = fmaf(tc, sk, -sm);
            cm = ck; sm = sk;
            ck = cn_; sk = sn_;
            cr[k] += ck; ci[k] += sk;
        }
    }
    #pragma unroll
    for (int i = 0; i < NPTS; ++i) {
        pecf[(size_t)((ch * NPTS + i) * 2 + 0) * KDIR + c] = cr[i];
        pecf[(size_t)((ch * NPTS + i) * 2 + 1) * KDIR + c] = ci[i];
    }
}

// K4: chunk reduce REVERTED to the r3 two-stage form. The r7/r8 merged
// ecf_fin streamed 17.8 MB through only 34 blocks (13% of CUs) — ~20us,
// a Guideline-11 violation that canceled the gemm win. p2a uses 544
// blocks (full chip), p2b then reads only 2.2 MB.
__global__ __launch_bounds__(256) void ecf_p2a(const float* __restrict__ pecf,
                                               double* __restrict__ pec2) {
    const int b = blockIdx.x;
    const int i = b >> 5;                 // 0..16
    const int r = b & 31;
    const int g = r >> 1;                 // 0..15
    const int half = r & 1;
    const int c = half * 256 + threadIdx.x;
    double sc = 0.0, ss = 0.0;
    #pragma unroll
    for (int k = 0; k < 16; ++k) {
        const int ch = g * 16 + k;
        sc += (double)pecf[(size_t)((ch * NPTS + i) * 2 + 0) * KDIR + c];
        ss += (double)pecf[(size_t)((ch * NPTS + i) * 2 + 1) * KDIR + c];
    }
    pec2[(size_t)((i * 16 + g) * 2 + 0) * KDIR + c] = sc;
    pec2[(size_t)((i * 16 + g) * 2 + 1) * KDIR + c] = ss;
}

// K5: finish (r3 form): sum 16 groups, integrand, block-reduce, atomic.
__global__ __launch_bounds__(256) void ecf_p2b(const double* __restrict__ pec2,
                                               float* __restrict__ out) {
    const int i = blockIdx.x >> 1;
    const int c = (blockIdx.x & 1) * 256 + threadIdx.x;
    double sc = 0.0, ss = 0.0;
    #pragma unroll
    for (int g = 0; g < 16; ++g) {
        sc += pec2[(size_t)((i * 16 + g) * 2 + 0) * KDIR + c];
        ss += pec2[(size_t)((i * 16 + g) * 2 + 1) * KDIR + c];
    }
    const double R = sc / (double)BATCH;
    const double I = ss / (double)BATCH;
    const double t = (2.0 / 17.0) * (double)(i + 1);
    const double tau = exp(-0.5 * t * t);
    const double w = (i == 0 || i == NPTS - 1) ? (1.0 / 17.0) : (2.0 / 17.0);
    const double dR = R - tau;
    double contrib = w * (dR * dR + I * I) / (double)KDIR;

    __shared__ double red[256];
    red[threadIdx.x] = contrib;
    __syncthreads();
    for (int s = 128; s > 0; s >>= 1) {
        if (threadIdx.x < s) red[threadIdx.x] += red[threadIdx.x + s];
        __syncthreads();
    }
    if (threadIdx.x == 0) atomicAdd(out, (float)red[0]);
}

// ---------------------------------------------------------------------------
extern "C" void kernel_launch(void* const* d_in, const int* in_sizes, int n_in,
                              void* d_out, int out_size, void* d_ws, size_t ws_size,
                              hipStream_t stream) {
    const float* emb = (const float*)d_in[0];   // (8192, 2048) fp32
    const float* dir = (const float*)d_in[1];   // (2048, 512) fp32
    float* out = (float*)d_out;

    char* ws = (char*)d_ws;
    // pecf/pec2 alias the A16 region (dead after GEMM).
    _Float16* A16  = (_Float16*)(ws + 0);               // 33,554,432 B
    float*    pecf = (float*)   (ws + 0);               // 17,825,792 B (after GEMM)
    double*   pec2 = (double*)  (ws + 17825792);        //  2,228,224 B (after GEMM)
    _Float16* dT   = (_Float16*)(ws + 33554432);        //  2,097,152 B
    _Float16* proj = (_Float16*)(ws + 35651584);        //  8,388,608 B
    float*    pp   = (float*)   (ws + 44040192);        //      4,096 B

    prep<<<8256, 256, 0, stream>>>(emb, dir, A16, dT, pp, out);
    gemm16<<<dim3(BATCH / 128, KDIR / 64), 256, 0, stream>>>(A16, dT, proj, pp);
    ecf_p1<<<512, 256, 0, stream>>>(proj, pp, pecf);
    ecf_p2a<<<544, 256, 0, stream>>>(pecf, pec2);
    ecf_p2b<<<34, 256, 0, stream>>>(pec2, out);
}